// Round 1
// baseline (3426.825 us; speedup 1.0000x reference)
//
#include <hip/hip_runtime.h>

static constexpr int kN   = 50000;
static constexpr int kDin = 256;
static constexpr int kC   = 8;
static constexpr int kE   = 1600000;
static constexpr int kSteps = 5;

// ws layout (bytes)
static constexpr size_t OFF_LOGB0 = 0;                       // kN*8*4 = 1,600,000
static constexpr size_t OFF_AGG   = 1600000;                 // kN*8*4 = 1,600,000
static constexpr size_t OFF_MSGA  = 3200000;                 // kE*8*4 = 51,200,000
static constexpr size_t OFF_MSGB  = 54400000;                // kE*8*4 = 51,200,000
static constexpr size_t WS_NEEDED = 105600000;

// ---------------------------------------------------------------------------
// Phase 1: log_b0 = log_softmax(x @ W + b); log_b = log_b0; agg = 0
// wave-per-row: lane l holds W rows {l, l+64, l+128, l+192} in registers.
// ---------------------------------------------------------------------------
__global__ void __launch_bounds__(256) phase1_kernel(
    const float* __restrict__ x, const float* __restrict__ W,
    const float* __restrict__ bias,
    float* __restrict__ log_b0, float* __restrict__ log_b,
    float* __restrict__ agg)
{
    const int lane   = threadIdx.x & 63;
    const int wave   = (blockIdx.x * blockDim.x + threadIdx.x) >> 6;
    const int nwaves = (gridDim.x * blockDim.x) >> 6;

    float w[4][8];
#pragma unroll
    for (int j = 0; j < 4; ++j) {
        const float4* wp = reinterpret_cast<const float4*>(W + (size_t)(lane + 64 * j) * kC);
        float4 a = wp[0], b2 = wp[1];
        w[j][0] = a.x;  w[j][1] = a.y;  w[j][2] = a.z;  w[j][3] = a.w;
        w[j][4] = b2.x; w[j][5] = b2.y; w[j][6] = b2.z; w[j][7] = b2.w;
    }

    for (int row = wave; row < kN; row += nwaves) {
        const float* xr = x + (size_t)row * kDin;
        float acc[8] = {0.f, 0.f, 0.f, 0.f, 0.f, 0.f, 0.f, 0.f};
#pragma unroll
        for (int j = 0; j < 4; ++j) {
            float xv = xr[lane + 64 * j];
#pragma unroll
            for (int c = 0; c < 8; ++c) acc[c] = fmaf(xv, w[j][c], acc[c]);
        }
#pragma unroll
        for (int off = 32; off > 0; off >>= 1) {
#pragma unroll
            for (int c = 0; c < 8; ++c) acc[c] += __shfl_down(acc[c], off, 64);
        }
        if (lane == 0) {
            float z[8], m = -1e30f;
#pragma unroll
            for (int c = 0; c < 8; ++c) { z[c] = acc[c] + bias[c]; m = fmaxf(m, z[c]); }
            float s = 0.f;
#pragma unroll
            for (int c = 0; c < 8; ++c) s += __expf(z[c] - m);
            float lse = m + __logf(s);
#pragma unroll
            for (int c = 0; c < 8; ++c) {
                float v = z[c] - lse;
                log_b0[(size_t)row * 8 + c] = v;
                log_b[(size_t)row * 8 + c]  = v;
                agg[(size_t)row * 8 + c]    = 0.f;
            }
        }
    }
}

// ---------------------------------------------------------------------------
// Edge kernel: per edge e,
//   t = log_b[src] - msg_old[rv]        (FIRST: msg_old is constant -> cancels)
//   p = softmax(t)
//   msg[c] = log((1-A)*p[c] + A) - log(1+7A)       (exact; A = e^-3)
//   msg_new[e] = msg;  atomicAdd(agg[dst], msg)
// ---------------------------------------------------------------------------
template <bool FIRST>
__global__ void __launch_bounds__(256) edge_kernel(
    const int* __restrict__ src, const int* __restrict__ dst,
    const int* __restrict__ rv,
    const float* __restrict__ log_b,
    const float* __restrict__ msg_old,
    float* __restrict__ msg_new,
    float* __restrict__ agg)
{
    const int e = blockIdx.x * blockDim.x + threadIdx.x;
    if (e >= kE) return;
    const int s = src[e];
    const int d = dst[e];

    float t[8];
    {
        const float4* lb = reinterpret_cast<const float4*>(log_b + (size_t)s * 8);
        float4 a = lb[0], b2 = lb[1];
        t[0] = a.x;  t[1] = a.y;  t[2] = a.z;  t[3] = a.w;
        t[4] = b2.x; t[5] = b2.y; t[6] = b2.z; t[7] = b2.w;
    }
    if (!FIRST) {
        const int r = rv[e];
        const float4* mo = reinterpret_cast<const float4*>(msg_old + (size_t)r * 8);
        float4 a = mo[0], b2 = mo[1];
        t[0] -= a.x;  t[1] -= a.y;  t[2] -= a.z;  t[3] -= a.w;
        t[4] -= b2.x; t[5] -= b2.y; t[6] -= b2.z; t[7] -= b2.w;
    }

    float m = t[0];
#pragma unroll
    for (int c = 1; c < 8; ++c) m = fmaxf(m, t[c]);
    float p[8], S = 0.f;
#pragma unroll
    for (int c = 0; c < 8; ++c) { p[c] = __expf(t[c] - m); S += p[c]; }

    const float A       = 0.049787068367863944f;  // e^-3
    const float coef    = 0.950212931632136f / S; // (1-A)/S
    const float LOG1P7A = 0.29899999871f;         // log(1 + 7A)

    float o[8];
#pragma unroll
    for (int c = 0; c < 8; ++c) o[c] = __logf(fmaf(coef, p[c], A)) - LOG1P7A;

    float4* mn = reinterpret_cast<float4*>(msg_new + (size_t)e * 8);
    mn[0] = make_float4(o[0], o[1], o[2], o[3]);
    mn[1] = make_float4(o[4], o[5], o[6], o[7]);

    float* ag = agg + (size_t)d * 8;
#pragma unroll
    for (int c = 0; c < 8; ++c) atomicAdd(ag + c, o[c]);
}

// ---------------------------------------------------------------------------
// Node kernel: log_b = log_normalize(agg + log_b0); agg = 0 (for next step)
// ---------------------------------------------------------------------------
__global__ void __launch_bounds__(256) node_kernel(
    float* __restrict__ agg, const float* __restrict__ log_b0,
    float* __restrict__ log_b)
{
    const int n = blockIdx.x * blockDim.x + threadIdx.x;
    if (n >= kN) return;
    float4* ag = reinterpret_cast<float4*>(agg + (size_t)n * 8);
    const float4* lb0 = reinterpret_cast<const float4*>(log_b0 + (size_t)n * 8);
    float4 a0 = ag[0], a1 = ag[1];
    float4 c0 = lb0[0], c1 = lb0[1];
    float v[8] = {a0.x + c0.x, a0.y + c0.y, a0.z + c0.z, a0.w + c0.w,
                  a1.x + c1.x, a1.y + c1.y, a1.z + c1.z, a1.w + c1.w};
    float m = v[0];
#pragma unroll
    for (int c = 1; c < 8; ++c) m = fmaxf(m, v[c]);
    float s = 0.f;
#pragma unroll
    for (int c = 0; c < 8; ++c) s += __expf(v[c] - m);
    float lse = m + __logf(s);
    float4* lb = reinterpret_cast<float4*>(log_b + (size_t)n * 8);
    lb[0] = make_float4(v[0] - lse, v[1] - lse, v[2] - lse, v[3] - lse);
    lb[1] = make_float4(v[4] - lse, v[5] - lse, v[6] - lse, v[7] - lse);
    float4 z = make_float4(0.f, 0.f, 0.f, 0.f);
    ag[0] = z;
    ag[1] = z;
}

extern "C" void kernel_launch(void* const* d_in, const int* in_sizes, int n_in,
                              void* d_out, int out_size, void* d_ws, size_t ws_size,
                              hipStream_t stream) {
    const float* x    = (const float*)d_in[0];
    const float* W    = (const float*)d_in[1];
    const float* bias = (const float*)d_in[2];
    const int*   ei   = (const int*)d_in[3];
    const int*   rv   = (const int*)d_in[4];
    const int* src = ei;
    const int* dst = ei + kE;
    float* out = (float*)d_out;

    if (ws_size < WS_NEEDED) return;  // cannot run without scratch

    char* ws = (char*)d_ws;
    float* log_b0 = (float*)(ws + OFF_LOGB0);
    float* agg    = (float*)(ws + OFF_AGG);
    float* msgA   = (float*)(ws + OFF_MSGA);
    float* msgB   = (float*)(ws + OFF_MSGB);

    const int edgeBlocks = (kE + 255) / 256;  // 6250
    const int nodeBlocks = (kN + 255) / 256;  // 196

    phase1_kernel<<<512, 256, 0, stream>>>(x, W, bias, log_b0, out, agg);

    // step 0: initial msg is uniform -> constant offset cancels in softmax
    edge_kernel<true><<<edgeBlocks, 256, 0, stream>>>(src, dst, rv, out, msgB, msgA, agg);
    node_kernel<<<nodeBlocks, 256, 0, stream>>>(agg, log_b0, out);

    float* cur = msgA;
    float* nxt = msgB;
    for (int it = 1; it < kSteps; ++it) {
        edge_kernel<false><<<edgeBlocks, 256, 0, stream>>>(src, dst, rv, out, cur, nxt, agg);
        node_kernel<<<nodeBlocks, 256, 0, stream>>>(agg, log_b0, out);
        float* tmp = cur; cur = nxt; nxt = tmp;
    }
}

// Round 3
// 623.087 us; speedup vs baseline: 5.4998x; 5.4998x over previous
//
#include <hip/hip_runtime.h>

static constexpr int kN   = 50000;
static constexpr int kDin = 256;
static constexpr int kC   = 8;
static constexpr int kE   = 1600000;
static constexpr int kSteps = 5;

// ---------------- ws layout (bytes), all offsets 64B-aligned ----------------
static constexpr size_t OFF_LOGB0 = 0;           // kN*8*4      = 1,600,000
static constexpr size_t OFF_START = 1600000;     // (kN+1)*4    = 200,004
static constexpr size_t OFF_DEG   = 1800064;     // kN*4        = 200,000  (deg, then cursor)
static constexpr size_t OFF_BSUM  = 2000128;     // 256*4       = 1,024
static constexpr size_t OFF_SPOS  = 2001408;     // kE*4        = 6,400,000
static constexpr size_t OFF_SRCS  = 8401664;     // kE*4        = 6,400,000
static constexpr size_t OFF_RVS   = 14801664;    // kE*4        = 6,400,000
static constexpr size_t OFF_MSGA  = 21201664;    // kE*8*2      = 25,600,000
static constexpr size_t OFF_MSGB  = 46801664;    // kE*8*2      = 25,600,000
static constexpr size_t WS_NEEDED = 72401664;

// quantization: o = log((1-A)p + A) - K,  A=e^-3, K=log(1+7A); o in [-3-K, -K], width exactly 3
// q = round((o + 3 + K) * 65535/3);  decode o = q*(3/65535) - (3+K)
static constexpr float kDEC   = 3.0f / 65535.0f;       // 4.57771e-5
static constexpr float kENC   = 65535.0f / 3.0f;       // 21845.0
static constexpr float kOFF   = 3.2990003f;            // 3 + K
static constexpr float kA     = 0.049787068367863944f; // e^-3
static constexpr float kOneMA = 0.950212931632136f;    // 1 - A

// ---------------------------------------------------------------------------
// Phase 1: log_b0 = log_softmax(x @ W + b); log_b(=out) = log_b0
// wave-per-row; lane l holds W rows {l, l+64, l+128, l+192}
// ---------------------------------------------------------------------------
__global__ void __launch_bounds__(256) phase1_kernel(
    const float* __restrict__ x, const float* __restrict__ W,
    const float* __restrict__ bias,
    float* __restrict__ log_b0, float* __restrict__ log_b)
{
    const int lane   = threadIdx.x & 63;
    const int wave   = (blockIdx.x * blockDim.x + threadIdx.x) >> 6;
    const int nwaves = (gridDim.x * blockDim.x) >> 6;

    float w[4][8];
#pragma unroll
    for (int j = 0; j < 4; ++j) {
        const float4* wp = reinterpret_cast<const float4*>(W + (size_t)(lane + 64 * j) * kC);
        float4 a = wp[0], b2 = wp[1];
        w[j][0] = a.x;  w[j][1] = a.y;  w[j][2] = a.z;  w[j][3] = a.w;
        w[j][4] = b2.x; w[j][5] = b2.y; w[j][6] = b2.z; w[j][7] = b2.w;
    }

    for (int row = wave; row < kN; row += nwaves) {
        const float* xr = x + (size_t)row * kDin;
        float acc[8] = {0.f, 0.f, 0.f, 0.f, 0.f, 0.f, 0.f, 0.f};
#pragma unroll
        for (int j = 0; j < 4; ++j) {
            float xv = xr[lane + 64 * j];
#pragma unroll
            for (int c = 0; c < 8; ++c) acc[c] = fmaf(xv, w[j][c], acc[c]);
        }
#pragma unroll
        for (int off = 32; off > 0; off >>= 1) {
#pragma unroll
            for (int c = 0; c < 8; ++c) acc[c] += __shfl_down(acc[c], off, 64);
        }
        if (lane == 0) {
            float z[8], m = -1e30f;
#pragma unroll
            for (int c = 0; c < 8; ++c) { z[c] = acc[c] + bias[c]; m = fmaxf(m, z[c]); }
            float s = 0.f;
#pragma unroll
            for (int c = 0; c < 8; ++c) s += __expf(z[c] - m);
            float lse = m + __logf(s);
#pragma unroll
            for (int c = 0; c < 8; ++c) {
                float v = z[c] - lse;
                log_b0[(size_t)row * 8 + c] = v;
                log_b[(size_t)row * 8 + c]  = v;
            }
        }
    }
}

// ---------------------------------------------------------------------------
// Preprocess: counting sort of edges by dst
// ---------------------------------------------------------------------------
__global__ void __launch_bounds__(256) hist_kernel(
    const int* __restrict__ dst, int* __restrict__ deg)
{
    const int e = blockIdx.x * blockDim.x + threadIdx.x;
    if (e < kE) atomicAdd(&deg[dst[e]], 1);
}

// block-local inclusive scan of deg -> start[i+1] (pre-offset), blocksum[b]
__global__ void __launch_bounds__(256) scan_a_kernel(
    const int* __restrict__ deg, int* __restrict__ start, int* __restrict__ bsum)
{
    __shared__ int sh[256];
    const int tid = threadIdx.x;
    const int i = blockIdx.x * 256 + tid;
    int v = (i < kN) ? deg[i] : 0;
    sh[tid] = v;
    __syncthreads();
#pragma unroll
    for (int off = 1; off < 256; off <<= 1) {
        int t = (tid >= off) ? sh[tid - off] : 0;
        __syncthreads();
        sh[tid] += t;
        __syncthreads();
    }
    if (i < kN) start[i + 1] = sh[tid];
    if (tid == 255) bsum[blockIdx.x] = sh[255];
}

// exclusive scan of 196 block sums (single block)
__global__ void __launch_bounds__(256) scan_b_kernel(int* __restrict__ bsum, int nblk)
{
    __shared__ int sh[256];
    const int tid = threadIdx.x;
    int v = (tid < nblk) ? bsum[tid] : 0;
    sh[tid] = v;
    __syncthreads();
#pragma unroll
    for (int off = 1; off < 256; off <<= 1) {
        int t = (tid >= off) ? sh[tid - off] : 0;
        __syncthreads();
        sh[tid] += t;
        __syncthreads();
    }
    if (tid < nblk) bsum[tid] = sh[tid] - v;  // exclusive
}

__global__ void __launch_bounds__(256) scan_c_kernel(
    int* __restrict__ start, const int* __restrict__ bsum)
{
    const int tid = threadIdx.x;
    const int i = blockIdx.x * 256 + tid;
    if (i < kN) start[i + 1] += bsum[blockIdx.x];
    if (i == 0) start[0] = 0;
}

// scatter: p = cursor[dst[e]]++ ; sortedpos[e] = p ; src_s[p] = src[e]
__global__ void __launch_bounds__(256) scatter_kernel(
    const int* __restrict__ src, const int* __restrict__ dst,
    int* __restrict__ cursor, int* __restrict__ spos, int* __restrict__ src_s)
{
    const int e = blockIdx.x * blockDim.x + threadIdx.x;
    if (e >= kE) return;
    const int p = atomicAdd(&cursor[dst[e]], 1);
    spos[e] = p;
    src_s[p] = src[e];
}

// remap rv into sorted coordinates: rv_s[pos(e)] = pos(rv[e])
__global__ void __launch_bounds__(256) remap_kernel(
    const int* __restrict__ rv, const int* __restrict__ spos,
    int* __restrict__ rv_s)
{
    const int e = blockIdx.x * blockDim.x + threadIdx.x;
    if (e >= kE) return;
    rv_s[spos[e]] = spos[rv[e]];
}

// ---------------------------------------------------------------------------
// Edge kernel (sorted order): t = log_b[src_s[i]] - dec(msg_old[rv_s[i]])
//   p = softmax(t); msg[c] = log((1-A)*p[c] + A) - K, quantized to u16
// (uniform decode offset cancels in softmax; FIRST step: uniform msg cancels)
// ---------------------------------------------------------------------------
template <bool FIRST>
__global__ void __launch_bounds__(256) edge_kernel(
    const int* __restrict__ src_s, const int* __restrict__ rv_s,
    const float* __restrict__ log_b,
    const unsigned short* __restrict__ mold,
    unsigned short* __restrict__ mnew)
{
    const int i = blockIdx.x * blockDim.x + threadIdx.x;
    if (i >= kE) return;
    const int s = src_s[i];

    float t[8];
    {
        const float4* lb = reinterpret_cast<const float4*>(log_b + (size_t)s * 8);
        float4 a = lb[0], b2 = lb[1];
        t[0] = a.x;  t[1] = a.y;  t[2] = a.z;  t[3] = a.w;
        t[4] = b2.x; t[5] = b2.y; t[6] = b2.z; t[7] = b2.w;
    }
    if (!FIRST) {
        const int r = rv_s[i];
        uint4 m = *reinterpret_cast<const uint4*>(mold + (size_t)r * 8);
        t[0] -= (float)(m.x & 0xffffu) * kDEC;
        t[1] -= (float)(m.x >> 16)     * kDEC;
        t[2] -= (float)(m.y & 0xffffu) * kDEC;
        t[3] -= (float)(m.y >> 16)     * kDEC;
        t[4] -= (float)(m.z & 0xffffu) * kDEC;
        t[5] -= (float)(m.z >> 16)     * kDEC;
        t[6] -= (float)(m.w & 0xffffu) * kDEC;
        t[7] -= (float)(m.w >> 16)     * kDEC;
    }

    float mx = t[0];
#pragma unroll
    for (int c = 1; c < 8; ++c) mx = fmaxf(mx, t[c]);
    float p[8], S = 0.f;
#pragma unroll
    for (int c = 0; c < 8; ++c) { p[c] = __expf(t[c] - mx); S += p[c]; }

    const float coef = kOneMA / S;
    unsigned int q[8];
#pragma unroll
    for (int c = 0; c < 8; ++c) {
        float u  = fmaf(coef, p[c], kA);                 // in [A, ~1]
        float qq = fmaf(__logf(u), kENC, 65535.0f);      // (log(u)+3)*65535/3
        qq = fminf(fmaxf(qq + 0.5f, 0.0f), 65535.0f);
        q[c] = (unsigned int)qq;
    }
    uint4 outv = make_uint4(q[0] | (q[1] << 16), q[2] | (q[3] << 16),
                            q[4] | (q[5] << 16), q[6] | (q[7] << 16));
    *reinterpret_cast<uint4*>(mnew + (size_t)i * 8) = outv;
}

// ---------------------------------------------------------------------------
// Node kernel: wave per node, streaming segmented sum (exact integer sum)
//   agg[c] = sum_j dec(msg[j][c]) = Q[c]*kDEC - deg*kOFF
//   log_b = log_normalize(agg + log_b0)
// ---------------------------------------------------------------------------
__global__ void __launch_bounds__(256) node_kernel(
    const int* __restrict__ start, const unsigned short* __restrict__ msgq,
    const float* __restrict__ log_b0, float* __restrict__ log_b)
{
    const int gtid = blockIdx.x * blockDim.x + threadIdx.x;
    const int n = gtid >> 6;
    if (n >= kN) return;
    const int lane = threadIdx.x & 63;
    const int sub = lane >> 3, c = lane & 7;
    const int s = start[n], e2 = start[n + 1];

    int Q = 0;
    for (int j = s + sub; j < e2; j += 8)
        Q += (int)msgq[(size_t)j * 8 + c];
    Q += __shfl_xor(Q, 8, 64);
    Q += __shfl_xor(Q, 16, 64);
    Q += __shfl_xor(Q, 32, 64);

    const int deg = e2 - s;
    float v = fmaf((float)Q, kDEC, -kOFF * (float)deg) + log_b0[(size_t)n * 8 + c];

    float m = v;
    m = fmaxf(m, __shfl_xor(m, 1, 64));
    m = fmaxf(m, __shfl_xor(m, 2, 64));
    m = fmaxf(m, __shfl_xor(m, 4, 64));
    float sum = __expf(v - m);
    sum += __shfl_xor(sum, 1, 64);
    sum += __shfl_xor(sum, 2, 64);
    sum += __shfl_xor(sum, 4, 64);
    float lse = m + __logf(sum);

    if (sub == 0) log_b[(size_t)n * 8 + c] = v - lse;
}

extern "C" void kernel_launch(void* const* d_in, const int* in_sizes, int n_in,
                              void* d_out, int out_size, void* d_ws, size_t ws_size,
                              hipStream_t stream) {
    const float* x    = (const float*)d_in[0];
    const float* W    = (const float*)d_in[1];
    const float* bias = (const float*)d_in[2];
    const int*   ei   = (const int*)d_in[3];
    const int*   rv   = (const int*)d_in[4];
    const int* src = ei;
    const int* dst = ei + kE;
    float* out = (float*)d_out;

    if (ws_size < WS_NEEDED) return;

    char* ws = (char*)d_ws;
    float* log_b0 = (float*)(ws + OFF_LOGB0);
    int*   start  = (int*)(ws + OFF_START);
    int*   deg    = (int*)(ws + OFF_DEG);    // reused as cursor after scan
    int*   bsum   = (int*)(ws + OFF_BSUM);
    int*   spos   = (int*)(ws + OFF_SPOS);
    int*   src_s  = (int*)(ws + OFF_SRCS);
    int*   rv_s   = (int*)(ws + OFF_RVS);
    unsigned short* msgA = (unsigned short*)(ws + OFF_MSGA);
    unsigned short* msgB = (unsigned short*)(ws + OFF_MSGB);

    const int edgeBlocks = (kE + 255) / 256;   // 6250
    const int scanBlocks = (kN + 255) / 256;   // 196
    const int nodeBlocks = (kN * 64 + 255) / 256;  // 12500 (wave per node)

    hipMemsetAsync(deg, 0, (size_t)kN * sizeof(int), stream);
    phase1_kernel<<<1024, 256, 0, stream>>>(x, W, bias, log_b0, out);

    hist_kernel<<<edgeBlocks, 256, 0, stream>>>(dst, deg);
    scan_a_kernel<<<scanBlocks, 256, 0, stream>>>(deg, start, bsum);
    scan_b_kernel<<<1, 256, 0, stream>>>(bsum, scanBlocks);
    scan_c_kernel<<<scanBlocks, 256, 0, stream>>>(start, bsum);
    hipMemcpyAsync(deg, start, (size_t)kN * sizeof(int),
                   hipMemcpyDeviceToDevice, stream);  // deg -> cursor
    scatter_kernel<<<edgeBlocks, 256, 0, stream>>>(src, dst, deg, spos, src_s);
    remap_kernel<<<edgeBlocks, 256, 0, stream>>>(rv, spos, rv_s);

    // step 0 (uniform initial msg cancels in softmax)
    edge_kernel<true><<<edgeBlocks, 256, 0, stream>>>(src_s, rv_s, out, msgB, msgA);
    node_kernel<<<nodeBlocks, 256, 0, stream>>>(start, msgA, log_b0, out);

    unsigned short* cur = msgA;
    unsigned short* nxt = msgB;
    for (int it = 1; it < kSteps; ++it) {
        edge_kernel<false><<<edgeBlocks, 256, 0, stream>>>(src_s, rv_s, out, cur, nxt);
        node_kernel<<<nodeBlocks, 256, 0, stream>>>(start, nxt, log_b0, out);
        unsigned short* tmp = cur; cur = nxt; nxt = tmp;
    }
}

// Round 5
// 503.056 us; speedup vs baseline: 6.8120x; 1.2386x over previous
//
#include <hip/hip_runtime.h>

static constexpr int kN   = 50000;
static constexpr int kDin = 256;
static constexpr int kC   = 8;
static constexpr int kE   = 1600000;
static constexpr int kSteps = 5;

static constexpr int kNB        = 256;   // coarse buckets
static constexpr int kBucketW   = 196;   // nodes per bucket (196*256 >= 50000)
static constexpr int kChunk     = 4096;  // edges per bin block

// ---------------- ws layout (bytes) ----------------
static constexpr size_t OFF_LOGB0 = 0;           // kN*8*4   = 1,600,000
static constexpr size_t OFF_BHIST = 1600000;     // 256*4    = 1,024
static constexpr size_t OFF_GBASE = 1601024;     // 257*4    -> pad
static constexpr size_t OFF_GCUR  = 1602112;     // 257*4    -> pad
static constexpr size_t OFF_START = 1603200;     // (kN+1)*4 = 200,004
static constexpr size_t OFF_REC   = 1803264;     // kE*4     = 6,400,000
static constexpr size_t OFF_INV   = 8203264;     // kE*4     = 6,400,000
static constexpr size_t OFF_MSGA  = 14603264;    // kE*8*2   = 25,600,000
static constexpr size_t OFF_MSGB  = 40203264;    // kE*8*2   = 25,600,000
static constexpr size_t WS_NEEDED = 65803264;

// msg quantization: o = log((1-A)p + A) - K in [-3-K, -K], width exactly 3
static constexpr float kDEC   = 3.0f / 65535.0f;
static constexpr float kENC   = 65535.0f / 3.0f;
static constexpr float kOFF   = 3.2990003f;            // 3 + K
static constexpr float kA     = 0.049787068367863944f; // e^-3
static constexpr float kOneMA = 0.950212931632136f;    // 1 - A

// ---------------------------------------------------------------------------
// Phase 1: log_b0 = log_softmax(x @ W + b); log_b(=out) = log_b0
// ---------------------------------------------------------------------------
__global__ void __launch_bounds__(256) phase1_kernel(
    const float* __restrict__ x, const float* __restrict__ W,
    const float* __restrict__ bias,
    float* __restrict__ log_b0, float* __restrict__ log_b)
{
    const int lane   = threadIdx.x & 63;
    const int wave   = (blockIdx.x * blockDim.x + threadIdx.x) >> 6;
    const int nwaves = (gridDim.x * blockDim.x) >> 6;

    float w[4][8];
#pragma unroll
    for (int j = 0; j < 4; ++j) {
        const float4* wp = reinterpret_cast<const float4*>(W + (size_t)(lane + 64 * j) * kC);
        float4 a = wp[0], b2 = wp[1];
        w[j][0] = a.x;  w[j][1] = a.y;  w[j][2] = a.z;  w[j][3] = a.w;
        w[j][4] = b2.x; w[j][5] = b2.y; w[j][6] = b2.z; w[j][7] = b2.w;
    }

    for (int row = wave; row < kN; row += nwaves) {
        const float* xr = x + (size_t)row * kDin;
        float acc[8] = {0.f, 0.f, 0.f, 0.f, 0.f, 0.f, 0.f, 0.f};
#pragma unroll
        for (int j = 0; j < 4; ++j) {
            float xv = xr[lane + 64 * j];
#pragma unroll
            for (int c = 0; c < 8; ++c) acc[c] = fmaf(xv, w[j][c], acc[c]);
        }
#pragma unroll
        for (int off = 32; off > 0; off >>= 1) {
#pragma unroll
            for (int c = 0; c < 8; ++c) acc[c] += __shfl_down(acc[c], off, 64);
        }
        if (lane == 0) {
            float z[8], m = -1e30f;
#pragma unroll
            for (int c = 0; c < 8; ++c) { z[c] = acc[c] + bias[c]; m = fmaxf(m, z[c]); }
            float s = 0.f;
#pragma unroll
            for (int c = 0; c < 8; ++c) s += __expf(z[c] - m);
            float lse = m + __logf(s);
#pragma unroll
            for (int c = 0; c < 8; ++c) {
                float v = z[c] - lse;
                log_b0[(size_t)row * 8 + c] = v;
                log_b[(size_t)row * 8 + c]  = v;
            }
        }
    }
}

// ---------------------------------------------------------------------------
// A1: coarse bucket histogram (bucket = dst / 196)
// ---------------------------------------------------------------------------
__global__ void __launch_bounds__(256) bucket_hist_kernel(
    const int* __restrict__ dst, int* __restrict__ bhist)
{
    __shared__ int h[kNB];
    h[threadIdx.x] = 0;
    __syncthreads();
    for (int e = blockIdx.x * blockDim.x + threadIdx.x; e < kE;
         e += gridDim.x * blockDim.x)
        atomicAdd(&h[dst[e] / kBucketW], 1);
    __syncthreads();
    if (h[threadIdx.x]) atomicAdd(&bhist[threadIdx.x], h[threadIdx.x]);
}

// ---------------------------------------------------------------------------
// A2: scan 256 bucket counts -> gbase[0..256]; gcur = gbase
// ---------------------------------------------------------------------------
__global__ void __launch_bounds__(256) bucket_scan_kernel(
    const int* __restrict__ bhist, int* __restrict__ gbase, int* __restrict__ gcur)
{
    __shared__ int sh[kNB];
    const int tid = threadIdx.x;
    int v = bhist[tid];
    sh[tid] = v;
    __syncthreads();
#pragma unroll
    for (int off = 1; off < kNB; off <<= 1) {
        int t = (tid >= off) ? sh[tid - off] : 0;
        __syncthreads();
        sh[tid] += t;
        __syncthreads();
    }
    int excl = sh[tid] - v;
    gbase[tid] = excl;
    gcur[tid]  = excl;
    if (tid == kNB - 1) { gbase[kNB] = sh[tid]; gcur[kNB] = sh[tid]; }
}

// ---------------------------------------------------------------------------
// A3: bin 4096-edge chunks into bucket-contiguous record runs.
// record u32 = (local_node << 21) | edge_id   (local < 196, e < 2^21)
// ---------------------------------------------------------------------------
__global__ void __launch_bounds__(256) bin_kernel(
    const int* __restrict__ dst, int* __restrict__ gcur,
    unsigned int* __restrict__ recbuf)
{
    __shared__ int hist[kNB];
    __shared__ int sh[kNB];
    __shared__ int cursor[kNB];
    __shared__ unsigned int buf[kChunk];

    const int tid = threadIdx.x;
    const int e0  = blockIdx.x * kChunk;
    const int n   = (kE - e0 < kChunk) ? (kE - e0) : kChunk;

    hist[tid] = 0;
    __syncthreads();

    int myb[16];
    unsigned int rec[16];
#pragma unroll
    for (int k = 0; k < 16; ++k) {
        const int i = tid + k * 256;
        myb[k] = -1;
        if (i < n) {
            const int d = dst[e0 + i];
            const int b = d / kBucketW;
            myb[k] = b;
            rec[k] = ((unsigned int)(d - b * kBucketW) << 21) | (unsigned int)(e0 + i);
            atomicAdd(&hist[b], 1);
        }
    }
    __syncthreads();

    // exclusive scan of hist
    const int cnt = hist[tid];
    sh[tid] = cnt;
    __syncthreads();
#pragma unroll
    for (int off = 1; off < kNB; off <<= 1) {
        int t = (tid >= off) ? sh[tid - off] : 0;
        __syncthreads();
        sh[tid] += t;
        __syncthreads();
    }
    const int excl = sh[tid] - cnt;
    cursor[tid] = excl;
    __syncthreads();

    // local scatter into LDS
#pragma unroll
    for (int k = 0; k < 16; ++k) {
        if (myb[k] >= 0) {
            int slot = atomicAdd(&cursor[myb[k]], 1);
            buf[slot] = rec[k];
        }
    }
    __syncthreads();

    // reserve global space & flush bucket runs (thread tid owns bucket tid)
    if (cnt > 0) {
        int gd = atomicAdd(&gcur[tid], cnt);
        for (int q = 0; q < cnt; ++q)
            recbuf[gd + q] = buf[excl + q];
    }
}

// ---------------------------------------------------------------------------
// B: per-bucket fine counting sort -> start[] (coalesced) and inv[] (hot region)
// ---------------------------------------------------------------------------
__global__ void __launch_bounds__(256) fine_kernel(
    const int* __restrict__ gbase, const unsigned int* __restrict__ recbuf,
    int* __restrict__ start, int* __restrict__ inv)
{
    __shared__ int hist[kNB];
    __shared__ int sh[kNB];
    __shared__ int lcur[kNB];

    const int tid = threadIdx.x;
    const int b   = blockIdx.x;
    const int nb0 = b * kBucketW;
    const int nnode = (kN - nb0 < kBucketW) ? (kN - nb0) : kBucketW;
    const int rb = gbase[b], re = gbase[b + 1];

    hist[tid] = 0;
    __syncthreads();

    for (int i = rb + tid; i < re; i += 256)
        atomicAdd(&hist[recbuf[i] >> 21], 1);
    __syncthreads();

    const int cnt = hist[tid];
    sh[tid] = cnt;
    __syncthreads();
#pragma unroll
    for (int off = 1; off < kNB; off <<= 1) {
        int t = (tid >= off) ? sh[tid - off] : 0;
        __syncthreads();
        sh[tid] += t;
        __syncthreads();
    }
    const int excl = sh[tid] - cnt;
    lcur[tid] = rb + excl;
    if (tid < nnode) start[nb0 + tid] = rb + excl;
    if (b == gridDim.x - 1 && tid == 0) start[kN] = kE;
    __syncthreads();

    for (int i = rb + tid; i < re; i += 256) {
        const unsigned int r = recbuf[i];
        const int p = atomicAdd(&lcur[r >> 21], 1);
        inv[p] = (int)(r & 0x1FFFFFu);
    }
}

// ---------------------------------------------------------------------------
// Edge kernel, ORIGINAL edge order: fully coalesced src/rv/mnew; gathers only.
//   t = log_b[src[e]] - dec(mold[rv[e]]);  p = softmax(t)
//   msg[c] = log((1-A)p[c] + A) - K  -> u16
// ---------------------------------------------------------------------------
template <bool FIRST>
__global__ void __launch_bounds__(256) edge_kernel(
    const int* __restrict__ src, const int* __restrict__ rv,
    const float* __restrict__ log_b,
    const unsigned short* __restrict__ mold,
    unsigned short* __restrict__ mnew)
{
    const int e = blockIdx.x * blockDim.x + threadIdx.x;
    if (e >= kE) return;
    const int s = src[e];

    float t[8];
    {
        const float4* lb = reinterpret_cast<const float4*>(log_b + (size_t)s * 8);
        float4 a = lb[0], b2 = lb[1];
        t[0] = a.x;  t[1] = a.y;  t[2] = a.z;  t[3] = a.w;
        t[4] = b2.x; t[5] = b2.y; t[6] = b2.z; t[7] = b2.w;
    }
    if (!FIRST) {
        const int r = rv[e];
        uint4 m = *reinterpret_cast<const uint4*>(mold + (size_t)r * 8);
        t[0] -= (float)(m.x & 0xffffu) * kDEC;
        t[1] -= (float)(m.x >> 16)     * kDEC;
        t[2] -= (float)(m.y & 0xffffu) * kDEC;
        t[3] -= (float)(m.y >> 16)     * kDEC;
        t[4] -= (float)(m.z & 0xffffu) * kDEC;
        t[5] -= (float)(m.z >> 16)     * kDEC;
        t[6] -= (float)(m.w & 0xffffu) * kDEC;
        t[7] -= (float)(m.w >> 16)     * kDEC;
    }

    float mx = t[0];
#pragma unroll
    for (int c = 1; c < 8; ++c) mx = fmaxf(mx, t[c]);
    float p[8], S = 0.f;
#pragma unroll
    for (int c = 0; c < 8; ++c) { p[c] = __expf(t[c] - mx); S += p[c]; }

    const float coef = kOneMA / S;
    unsigned int q[8];
#pragma unroll
    for (int c = 0; c < 8; ++c) {
        float u  = fmaf(coef, p[c], kA);
        float qq = fmaf(__logf(u), kENC, 65535.0f);
        qq = fminf(fmaxf(qq + 0.5f, 0.0f), 65535.0f);
        q[c] = (unsigned int)qq;
    }
    uint4 outv = make_uint4(q[0] | (q[1] << 16), q[2] | (q[3] << 16),
                            q[4] | (q[5] << 16), q[6] | (q[7] << 16));
    *reinterpret_cast<uint4*>(mnew + (size_t)e * 8) = outv;
}

// ---------------------------------------------------------------------------
// Node kernel: wave per node; exact integer segmented sum via inv[] gather.
// ---------------------------------------------------------------------------
__global__ void __launch_bounds__(256) node_kernel(
    const int* __restrict__ start, const int* __restrict__ inv,
    const unsigned short* __restrict__ msgq,
    const float* __restrict__ log_b0, float* __restrict__ log_b)
{
    const int gtid = blockIdx.x * blockDim.x + threadIdx.x;
    const int n = gtid >> 6;
    if (n >= kN) return;
    const int lane = threadIdx.x & 63;
    const int sub = lane >> 3, c = lane & 7;
    const int s = start[n], e2 = start[n + 1];

    int Q = 0;
    for (int j = s + sub; j < e2; j += 8)
        Q += (int)msgq[(size_t)inv[j] * 8 + c];
    Q += __shfl_xor(Q, 8, 64);
    Q += __shfl_xor(Q, 16, 64);
    Q += __shfl_xor(Q, 32, 64);

    const int deg = e2 - s;
    float v = fmaf((float)Q, kDEC, -kOFF * (float)deg) + log_b0[(size_t)n * 8 + c];

    float m = v;
    m = fmaxf(m, __shfl_xor(m, 1, 64));
    m = fmaxf(m, __shfl_xor(m, 2, 64));
    m = fmaxf(m, __shfl_xor(m, 4, 64));
    float sum = __expf(v - m);
    sum += __shfl_xor(sum, 1, 64);
    sum += __shfl_xor(sum, 2, 64);
    sum += __shfl_xor(sum, 4, 64);
    float lse = m + __logf(sum);

    if (sub == 0) log_b[(size_t)n * 8 + c] = v - lse;
}

extern "C" void kernel_launch(void* const* d_in, const int* in_sizes, int n_in,
                              void* d_out, int out_size, void* d_ws, size_t ws_size,
                              hipStream_t stream) {
    const float* x    = (const float*)d_in[0];
    const float* W    = (const float*)d_in[1];
    const float* bias = (const float*)d_in[2];
    const int*   ei   = (const int*)d_in[3];
    const int*   rv   = (const int*)d_in[4];
    const int* src = ei;
    const int* dst = ei + kE;
    float* out = (float*)d_out;

    if (ws_size < WS_NEEDED) return;

    char* ws = (char*)d_ws;
    float* log_b0 = (float*)(ws + OFF_LOGB0);
    int*   bhist  = (int*)(ws + OFF_BHIST);
    int*   gbase  = (int*)(ws + OFF_GBASE);
    int*   gcur   = (int*)(ws + OFF_GCUR);
    int*   start  = (int*)(ws + OFF_START);
    unsigned int* recbuf = (unsigned int*)(ws + OFF_REC);
    int*   inv    = (int*)(ws + OFF_INV);
    unsigned short* msgA = (unsigned short*)(ws + OFF_MSGA);
    unsigned short* msgB = (unsigned short*)(ws + OFF_MSGB);

    const int edgeBlocks = (kE + 255) / 256;         // 6250
    const int nodeBlocks = (kN * 64 + 255) / 256;    // 12500
    const int binBlocks  = (kE + kChunk - 1) / kChunk;  // 391

    (void)hipMemsetAsync(bhist, 0, kNB * sizeof(int), stream);
    phase1_kernel<<<1024, 256, 0, stream>>>(x, W, bias, log_b0, out);

    bucket_hist_kernel<<<256, 256, 0, stream>>>(dst, bhist);
    bucket_scan_kernel<<<1, 256, 0, stream>>>(bhist, gbase, gcur);
    bin_kernel<<<binBlocks, 256, 0, stream>>>(dst, gcur, recbuf);
    fine_kernel<<<kNB, 256, 0, stream>>>(gbase, recbuf, start, inv);

    // step 0 (uniform initial msg cancels in softmax)
    edge_kernel<true><<<edgeBlocks, 256, 0, stream>>>(src, rv, out, msgB, msgA);
    node_kernel<<<nodeBlocks, 256, 0, stream>>>(start, inv, msgA, log_b0, out);

    unsigned short* cur = msgA;
    unsigned short* nxt = msgB;
    for (int it = 1; it < kSteps; ++it) {
        edge_kernel<false><<<edgeBlocks, 256, 0, stream>>>(src, rv, out, cur, nxt);
        node_kernel<<<nodeBlocks, 256, 0, stream>>>(start, inv, nxt, log_b0, out);
        unsigned short* tmp = cur; cur = nxt; nxt = tmp;
    }
}

// Round 6
// 480.554 us; speedup vs baseline: 7.1310x; 1.0468x over previous
//
#include <hip/hip_runtime.h>

static constexpr int kN   = 50000;
static constexpr int kDin = 256;
static constexpr int kC   = 8;
static constexpr int kE   = 1600000;
static constexpr int kSteps = 5;

static constexpr int kNB        = 256;   // coarse buckets
static constexpr int kBucketW   = 196;   // nodes per bucket (196*256 >= 50000)
static constexpr int kChunk     = 4096;  // edges per bin block

// ---------------- ws layout (bytes) ----------------
static constexpr size_t OFF_LOGB0 = 0;           // kN*8*4   = 1,600,000
static constexpr size_t OFF_BHIST = 1600000;     // 256*4
static constexpr size_t OFF_GBASE = 1601024;     // 257*4 -> pad
static constexpr size_t OFF_GCUR  = 1602112;     // 257*4 -> pad
static constexpr size_t OFF_START = 1603200;     // (kN+1)*4
static constexpr size_t OFF_REC   = 1803264;     // kE*4
static constexpr size_t OFF_INV   = 8203264;     // kE*4
static constexpr size_t OFF_MSGA  = 14603264;    // kE*8*2
static constexpr size_t OFF_MSGB  = 40203264;    // kE*8*2
static constexpr size_t WS_NEEDED = 65803264;

// msg quantization: o = log((1-A)p + A) - K in [-3-K, -K], width exactly 3
static constexpr float kDEC   = 3.0f / 65535.0f;
static constexpr float kENC   = 65535.0f / 3.0f;
static constexpr float kOFF   = 3.2990003f;            // 3 + K
static constexpr float kA     = 0.049787068367863944f; // e^-3
static constexpr float kOneMA = 0.950212931632136f;    // 1 - A

// ---------------------------------------------------------------------------
// Fused init: blocks [0,1024) do phase1 (log_b0 = log_softmax(xW+b)),
//             blocks [1024,1280) do the coarse bucket histogram.
// ---------------------------------------------------------------------------
__global__ void __launch_bounds__(256) init_kernel(
    const float* __restrict__ x, const float* __restrict__ W,
    const float* __restrict__ bias,
    float* __restrict__ log_b0, float* __restrict__ log_b,
    const int* __restrict__ dst, int* __restrict__ bhist)
{
    __shared__ int h[kNB];
    if (blockIdx.x >= 1024) {
        // ---- histogram part ----
        h[threadIdx.x] = 0;
        __syncthreads();
        const int nthr = 256 * 256;
        for (int e = (blockIdx.x - 1024) * 256 + threadIdx.x; e < kE; e += nthr)
            atomicAdd(&h[dst[e] / kBucketW], 1);
        __syncthreads();
        if (h[threadIdx.x]) atomicAdd(&bhist[threadIdx.x], h[threadIdx.x]);
        return;
    }

    // ---- phase1 part: wave per row ----
    const int lane   = threadIdx.x & 63;
    const int wave   = (blockIdx.x * 256 + threadIdx.x) >> 6;
    const int nwaves = (1024 * 256) >> 6;

    float w[4][8];
#pragma unroll
    for (int j = 0; j < 4; ++j) {
        const float4* wp = reinterpret_cast<const float4*>(W + (size_t)(lane + 64 * j) * kC);
        float4 a = wp[0], b2 = wp[1];
        w[j][0] = a.x;  w[j][1] = a.y;  w[j][2] = a.z;  w[j][3] = a.w;
        w[j][4] = b2.x; w[j][5] = b2.y; w[j][6] = b2.z; w[j][7] = b2.w;
    }

    for (int row = wave; row < kN; row += nwaves) {
        const float* xr = x + (size_t)row * kDin;
        float acc[8] = {0.f, 0.f, 0.f, 0.f, 0.f, 0.f, 0.f, 0.f};
#pragma unroll
        for (int j = 0; j < 4; ++j) {
            float xv = xr[lane + 64 * j];
#pragma unroll
            for (int c = 0; c < 8; ++c) acc[c] = fmaf(xv, w[j][c], acc[c]);
        }
#pragma unroll
        for (int off = 32; off > 0; off >>= 1) {
#pragma unroll
            for (int c = 0; c < 8; ++c) acc[c] += __shfl_down(acc[c], off, 64);
        }
        if (lane == 0) {
            float z[8], m = -1e30f;
#pragma unroll
            for (int c = 0; c < 8; ++c) { z[c] = acc[c] + bias[c]; m = fmaxf(m, z[c]); }
            float s = 0.f;
#pragma unroll
            for (int c = 0; c < 8; ++c) s += __expf(z[c] - m);
            float lse = m + __logf(s);
#pragma unroll
            for (int c = 0; c < 8; ++c) {
                float v = z[c] - lse;
                log_b0[(size_t)row * 8 + c] = v;
                log_b[(size_t)row * 8 + c]  = v;
            }
        }
    }
}

// ---------------------------------------------------------------------------
// A2: scan 256 bucket counts -> gbase[0..256]; gcur = gbase
// ---------------------------------------------------------------------------
__global__ void __launch_bounds__(256) bucket_scan_kernel(
    const int* __restrict__ bhist, int* __restrict__ gbase, int* __restrict__ gcur)
{
    __shared__ int sh[kNB];
    const int tid = threadIdx.x;
    int v = bhist[tid];
    sh[tid] = v;
    __syncthreads();
#pragma unroll
    for (int off = 1; off < kNB; off <<= 1) {
        int t = (tid >= off) ? sh[tid - off] : 0;
        __syncthreads();
        sh[tid] += t;
        __syncthreads();
    }
    int excl = sh[tid] - v;
    gbase[tid] = excl;
    gcur[tid]  = excl;
    if (tid == kNB - 1) { gbase[kNB] = sh[tid]; gcur[kNB] = sh[tid]; }
}

// ---------------------------------------------------------------------------
// A3: bin 4096-edge chunks into bucket-contiguous record runs.
// record u32 = (local_node << 21) | edge_id.  Parallel coalesced flush.
// ---------------------------------------------------------------------------
__global__ void __launch_bounds__(256) bin_kernel(
    const int* __restrict__ dst, int* __restrict__ gcur,
    unsigned int* __restrict__ recbuf)
{
    __shared__ int hist[kNB];
    __shared__ int sh[kNB];
    __shared__ int cursor[kNB];
    __shared__ int gdbase[kNB];
    __shared__ unsigned int buf[kChunk];

    const int tid = threadIdx.x;
    const int e0  = blockIdx.x * kChunk;
    const int n   = (kE - e0 < kChunk) ? (kE - e0) : kChunk;

    hist[tid] = 0;
    __syncthreads();

    int myb[16];
    unsigned int rec[16];
#pragma unroll
    for (int k = 0; k < 16; ++k) {
        const int i = tid + k * 256;
        myb[k] = -1;
        if (i < n) {
            const int d = dst[e0 + i];
            const int b = d / kBucketW;
            myb[k] = b;
            rec[k] = ((unsigned int)(d - b * kBucketW) << 21) | (unsigned int)(e0 + i);
            atomicAdd(&hist[b], 1);
        }
    }
    __syncthreads();

    // inclusive scan of hist into sh
    const int cnt = hist[tid];
    sh[tid] = cnt;
    __syncthreads();
#pragma unroll
    for (int off = 1; off < kNB; off <<= 1) {
        int t = (tid >= off) ? sh[tid - off] : 0;
        __syncthreads();
        sh[tid] += t;
        __syncthreads();
    }
    const int excl = sh[tid] - cnt;
    cursor[tid] = excl;
    __syncthreads();

    // local scatter into LDS (bucket-sorted within chunk)
#pragma unroll
    for (int k = 0; k < 16; ++k) {
        if (myb[k] >= 0) {
            int slot = atomicAdd(&cursor[myb[k]], 1);
            buf[slot] = rec[k];
        }
    }
    // reserve global space per bucket
    gdbase[tid] = (cnt > 0) ? atomicAdd(&gcur[tid], cnt) : 0;
    __syncthreads();

    // parallel coalesced flush: slot i -> bucket via binary search on sh
    for (int i = tid; i < n; i += 256) {
        int b = 0;
#pragma unroll
        for (int step = 128; step >= 1; step >>= 1)
            if (b + step <= kNB - 1 && sh[b + step - 1] <= i) b += step;
        const int off_in_b = i - (sh[b] - hist[b]);
        recbuf[gdbase[b] + off_in_b] = buf[i];
    }
}

// ---------------------------------------------------------------------------
// B: per-bucket fine counting sort -> start[] (coalesced) and inv[] (hot region)
// ---------------------------------------------------------------------------
__global__ void __launch_bounds__(256) fine_kernel(
    const int* __restrict__ gbase, const unsigned int* __restrict__ recbuf,
    int* __restrict__ start, int* __restrict__ inv)
{
    __shared__ int hist[kNB];
    __shared__ int sh[kNB];
    __shared__ int lcur[kNB];

    const int tid = threadIdx.x;
    const int b   = blockIdx.x;
    const int nb0 = b * kBucketW;
    const int nnode = (kN - nb0 < kBucketW) ? (kN - nb0) : kBucketW;
    const int rb = gbase[b], re = gbase[b + 1];

    hist[tid] = 0;
    __syncthreads();

    for (int i = rb + tid; i < re; i += 256)
        atomicAdd(&hist[recbuf[i] >> 21], 1);
    __syncthreads();

    const int cnt = hist[tid];
    sh[tid] = cnt;
    __syncthreads();
#pragma unroll
    for (int off = 1; off < kNB; off <<= 1) {
        int t = (tid >= off) ? sh[tid - off] : 0;
        __syncthreads();
        sh[tid] += t;
        __syncthreads();
    }
    const int excl = sh[tid] - cnt;
    lcur[tid] = rb + excl;
    if (tid < nnode) start[nb0 + tid] = rb + excl;
    if (b == gridDim.x - 1 && tid == 0) start[kN] = kE;
    __syncthreads();

    for (int i = rb + tid; i < re; i += 256) {
        const unsigned int r = recbuf[i];
        const int p = atomicAdd(&lcur[r >> 21], 1);
        inv[p] = (int)(r & 0x1FFFFFu);
    }
}

// ---------------------------------------------------------------------------
// Edge kernel, ORIGINAL edge order, 2 edges/thread for MLP.
//   t = log_b[src[e]] - dec(mold[rv[e]]);  p = softmax(t)  (shift-invariant,
//   so unnormalized log_b is fine);  msg[c] = log((1-A)p[c]+A) - K -> u16
// ---------------------------------------------------------------------------
template <bool FIRST>
__global__ void __launch_bounds__(256) edge_kernel(
    const int* __restrict__ src, const int* __restrict__ rv,
    const float* __restrict__ log_b,
    const unsigned short* __restrict__ mold,
    unsigned short* __restrict__ mnew)
{
    const int e0 = (blockIdx.x * 256 + threadIdx.x) * 2;
    if (e0 >= kE) return;

    const int2 sp = *reinterpret_cast<const int2*>(src + e0);

    // issue all gathers first
    const float4* lba = reinterpret_cast<const float4*>(log_b + (size_t)sp.x * 8);
    const float4* lbb = reinterpret_cast<const float4*>(log_b + (size_t)sp.y * 8);
    float4 a0 = lba[0], a1 = lba[1];
    float4 b0 = lbb[0], b1 = lbb[1];

    uint4 ma, mb;
    if (!FIRST) {
        const int2 rp = *reinterpret_cast<const int2*>(rv + e0);
        ma = *reinterpret_cast<const uint4*>(mold + (size_t)rp.x * 8);
        mb = *reinterpret_cast<const uint4*>(mold + (size_t)rp.y * 8);
    }

    float ta[8] = {a0.x, a0.y, a0.z, a0.w, a1.x, a1.y, a1.z, a1.w};
    float tb[8] = {b0.x, b0.y, b0.z, b0.w, b1.x, b1.y, b1.z, b1.w};
    if (!FIRST) {
        ta[0] -= (float)(ma.x & 0xffffu) * kDEC;  ta[1] -= (float)(ma.x >> 16) * kDEC;
        ta[2] -= (float)(ma.y & 0xffffu) * kDEC;  ta[3] -= (float)(ma.y >> 16) * kDEC;
        ta[4] -= (float)(ma.z & 0xffffu) * kDEC;  ta[5] -= (float)(ma.z >> 16) * kDEC;
        ta[6] -= (float)(ma.w & 0xffffu) * kDEC;  ta[7] -= (float)(ma.w >> 16) * kDEC;
        tb[0] -= (float)(mb.x & 0xffffu) * kDEC;  tb[1] -= (float)(mb.x >> 16) * kDEC;
        tb[2] -= (float)(mb.y & 0xffffu) * kDEC;  tb[3] -= (float)(mb.y >> 16) * kDEC;
        tb[4] -= (float)(mb.z & 0xffffu) * kDEC;  tb[5] -= (float)(mb.z >> 16) * kDEC;
        tb[6] -= (float)(mb.w & 0xffffu) * kDEC;  tb[7] -= (float)(mb.w >> 16) * kDEC;
    }

    unsigned int qa[8], qb[8];
    {
        float mx = ta[0];
#pragma unroll
        for (int c = 1; c < 8; ++c) mx = fmaxf(mx, ta[c]);
        float p[8], S = 0.f;
#pragma unroll
        for (int c = 0; c < 8; ++c) { p[c] = __expf(ta[c] - mx); S += p[c]; }
        const float coef = kOneMA / S;
#pragma unroll
        for (int c = 0; c < 8; ++c) {
            float u  = fmaf(coef, p[c], kA);
            float qq = fmaf(__logf(u), kENC, 65535.0f);
            qq = fminf(fmaxf(qq + 0.5f, 0.0f), 65535.0f);
            qa[c] = (unsigned int)qq;
        }
    }
    {
        float mx = tb[0];
#pragma unroll
        for (int c = 1; c < 8; ++c) mx = fmaxf(mx, tb[c]);
        float p[8], S = 0.f;
#pragma unroll
        for (int c = 0; c < 8; ++c) { p[c] = __expf(tb[c] - mx); S += p[c]; }
        const float coef = kOneMA / S;
#pragma unroll
        for (int c = 0; c < 8; ++c) {
            float u  = fmaf(coef, p[c], kA);
            float qq = fmaf(__logf(u), kENC, 65535.0f);
            qq = fminf(fmaxf(qq + 0.5f, 0.0f), 65535.0f);
            qb[c] = (unsigned int)qq;
        }
    }

    uint4* mn = reinterpret_cast<uint4*>(mnew + (size_t)e0 * 8);
    mn[0] = make_uint4(qa[0] | (qa[1] << 16), qa[2] | (qa[3] << 16),
                       qa[4] | (qa[5] << 16), qa[6] | (qa[7] << 16));
    mn[1] = make_uint4(qb[0] | (qb[1] << 16), qb[2] | (qb[3] << 16),
                       qb[4] | (qb[5] << 16), qb[6] | (qb[7] << 16));
}

// ---------------------------------------------------------------------------
// Node kernel: 2 nodes per wave, one lane = one full edge (uint4 gather).
// Exact integer segmented sum; normalize only when FINAL (softmax shift-inv).
// ---------------------------------------------------------------------------
template <bool FINAL>
__global__ void __launch_bounds__(256) node_kernel(
    const int* __restrict__ start, const int* __restrict__ inv,
    const unsigned short* __restrict__ msgq,
    const float* __restrict__ log_b0, float* __restrict__ log_b)
{
    const int wid  = (blockIdx.x * 256 + threadIdx.x) >> 6;
    const int lane = threadIdx.x & 63;
    const int half = lane >> 5;
    const int l32  = lane & 31;
    const int n = wid * 2 + half;
    if (n >= kN) return;

    const int s = start[n], e2 = start[n + 1];

    int q[8] = {0, 0, 0, 0, 0, 0, 0, 0};
    for (int j = s + l32; j < e2; j += 32) {
        const uint4 m = *reinterpret_cast<const uint4*>(msgq + (size_t)inv[j] * 8);
        q[0] += (int)(m.x & 0xffffu);  q[1] += (int)(m.x >> 16);
        q[2] += (int)(m.y & 0xffffu);  q[3] += (int)(m.y >> 16);
        q[4] += (int)(m.z & 0xffffu);  q[5] += (int)(m.z >> 16);
        q[6] += (int)(m.w & 0xffffu);  q[7] += (int)(m.w >> 16);
    }
    // reduce within each 32-lane half (xor offsets stay inside the half)
#pragma unroll
    for (int off = 1; off <= 16; off <<= 1) {
#pragma unroll
        for (int c = 0; c < 8; ++c) q[c] += __shfl_xor(q[c], off, 64);
    }

    if (l32 == 0) {
        const int deg = e2 - s;
        const float base = -kOFF * (float)deg;
        const float4* lb0 = reinterpret_cast<const float4*>(log_b0 + (size_t)n * 8);
        float4 c0 = lb0[0], c1 = lb0[1];
        float v[8];
        v[0] = fmaf((float)q[0], kDEC, base) + c0.x;
        v[1] = fmaf((float)q[1], kDEC, base) + c0.y;
        v[2] = fmaf((float)q[2], kDEC, base) + c0.z;
        v[3] = fmaf((float)q[3], kDEC, base) + c0.w;
        v[4] = fmaf((float)q[4], kDEC, base) + c1.x;
        v[5] = fmaf((float)q[5], kDEC, base) + c1.y;
        v[6] = fmaf((float)q[6], kDEC, base) + c1.z;
        v[7] = fmaf((float)q[7], kDEC, base) + c1.w;
        if (FINAL) {
            float m = v[0];
#pragma unroll
            for (int c = 1; c < 8; ++c) m = fmaxf(m, v[c]);
            float sum = 0.f;
#pragma unroll
            for (int c = 0; c < 8; ++c) sum += __expf(v[c] - m);
            float lse = m + __logf(sum);
#pragma unroll
            for (int c = 0; c < 8; ++c) v[c] -= lse;
        }
        float4* lb = reinterpret_cast<float4*>(log_b + (size_t)n * 8);
        lb[0] = make_float4(v[0], v[1], v[2], v[3]);
        lb[1] = make_float4(v[4], v[5], v[6], v[7]);
    }
}

extern "C" void kernel_launch(void* const* d_in, const int* in_sizes, int n_in,
                              void* d_out, int out_size, void* d_ws, size_t ws_size,
                              hipStream_t stream) {
    const float* x    = (const float*)d_in[0];
    const float* W    = (const float*)d_in[1];
    const float* bias = (const float*)d_in[2];
    const int*   ei   = (const int*)d_in[3];
    const int*   rv   = (const int*)d_in[4];
    const int* src = ei;
    const int* dst = ei + kE;
    float* out = (float*)d_out;

    if (ws_size < WS_NEEDED) return;

    char* ws = (char*)d_ws;
    float* log_b0 = (float*)(ws + OFF_LOGB0);
    int*   bhist  = (int*)(ws + OFF_BHIST);
    int*   gbase  = (int*)(ws + OFF_GBASE);
    int*   gcur   = (int*)(ws + OFF_GCUR);
    int*   start  = (int*)(ws + OFF_START);
    unsigned int* recbuf = (unsigned int*)(ws + OFF_REC);
    int*   inv    = (int*)(ws + OFF_INV);
    unsigned short* msgA = (unsigned short*)(ws + OFF_MSGA);
    unsigned short* msgB = (unsigned short*)(ws + OFF_MSGB);

    const int edgeBlocks = (kE / 2 + 255) / 256;        // 3125
    const int nodeBlocks = ((kN + 1) / 2 * 64 + 255) / 256;  // 6250
    const int binBlocks  = (kE + kChunk - 1) / kChunk;  // 391

    (void)hipMemsetAsync(bhist, 0, kNB * sizeof(int), stream);
    init_kernel<<<1280, 256, 0, stream>>>(x, W, bias, log_b0, out, dst, bhist);
    bucket_scan_kernel<<<1, 256, 0, stream>>>(bhist, gbase, gcur);
    bin_kernel<<<binBlocks, 256, 0, stream>>>(dst, gcur, recbuf);
    fine_kernel<<<kNB, 256, 0, stream>>>(gbase, recbuf, start, inv);

    // step 0 (uniform initial msg cancels in softmax)
    edge_kernel<true><<<edgeBlocks, 256, 0, stream>>>(src, rv, out, msgB, msgA);
    node_kernel<false><<<nodeBlocks, 256, 0, stream>>>(start, inv, msgA, log_b0, out);

    unsigned short* cur = msgA;
    unsigned short* nxt = msgB;
    for (int it = 1; it < kSteps; ++it) {
        edge_kernel<false><<<edgeBlocks, 256, 0, stream>>>(src, rv, out, cur, nxt);
        if (it == kSteps - 1)
            node_kernel<true><<<nodeBlocks, 256, 0, stream>>>(start, inv, nxt, log_b0, out);
        else
            node_kernel<false><<<nodeBlocks, 256, 0, stream>>>(start, inv, nxt, log_b0, out);
        unsigned short* tmp = cur; cur = nxt; nxt = tmp;
    }
}